// Round 10
// baseline (814.838 us; speedup 1.0000x reference)
//
#include <hip/hip_runtime.h>
#include <math.h>

#define S 4096
#define B 16
#define R 8             // attention rows per wave

// ---------------------------------------------------------------------------
// Fused QKV — row-per-wave reduce-GEMM (probe-shaped).
// Model from R1-R9: loaded HBM latency ~6000cy -> need ~62KB in flight per
// CU; only the 100%-occupancy probe (32 waves x 2KB) achieved it. So:
// VGPR<=64 (8 waves/SIMD), each wave owns ONE W row and streams it
// contiguously with a named 2-deep double buffer (~1-2KB always in flight;
// low reg pressure so the compiler won't sink the prefetch like R5/R9).
// Lane l holds cols 4l..4l+3; p[16] per-lane partials over all batches;
// one 96-shuffle tree reduce per row amortized over 16KB of W.
// x windows come from L1/L2 (all waves sweep the same x window in phase).
// Grid: 3072 blocks x 4 waves = 12288 waves = 3 mats x 4096 rows.
// ---------------------------------------------------------------------------
__global__ __launch_bounds__(256, 8) void qkv_kernel(
    const float* __restrict__ x,
    const float* __restrict__ Wq, const float* __restrict__ bq,
    const float* __restrict__ Wk, const float* __restrict__ bk,
    const float* __restrict__ Wv, const float* __restrict__ bv,
    float* __restrict__ q, float* __restrict__ k, float* __restrict__ v)
{
    const int lane = threadIdx.x & 63;
    const int wave = threadIdx.x >> 6;
    const int task = blockIdx.x * 4 + wave;   // 0..12287
    const int mat  = task >> 12;              // 0:q 1:k 2:v
    const int row  = task & 4095;

    const float* W    = (mat == 0) ? Wq : (mat == 1) ? Wk : Wv;
    const float* bias = (mat == 0) ? bq : (mat == 1) ? bk : bv;
    float*       out  = (mat == 0) ? q  : (mat == 1) ? k  : v;

    const float* wp = W + (size_t)row * S + lane * 4;
    const float* xp = x + lane * 4;

    float p[16];
    #pragma unroll
    for (int b = 0; b < 16; ++b) p[b] = 0.f;

    #define QKV_FMA16(wv, wwin)                                            \
    {                                                                      \
        const float* xw = xp + (wwin) * 256;                               \
        _Pragma("unroll")                                                  \
        for (int b = 0; b < 16; ++b) {                                     \
            float4 xv = *(const float4*)&xw[(size_t)b * S];                \
            p[b] = fmaf(wv.x, xv.x, p[b]);                                 \
            p[b] = fmaf(wv.y, xv.y, p[b]);                                 \
            p[b] = fmaf(wv.z, xv.z, p[b]);                                 \
            p[b] = fmaf(wv.w, xv.w, p[b]);                                 \
        }                                                                  \
    }

    // named double-buffer sweep of the row: 16 windows x 1 KB, contiguous
    float4 wa = *(const float4*)&wp[0];
    #pragma unroll 1
    for (int ww = 0; ww < 8; ++ww) {
        float4 wb = *(const float4*)&wp[(2 * ww + 1) * 256];
        QKV_FMA16(wa, 2 * ww);
        if (ww < 7) wa = *(const float4*)&wp[(2 * ww + 2) * 256];
        QKV_FMA16(wb, 2 * ww + 1);
    }
    #undef QKV_FMA16

    // tree-reduce each p[b] across 64 lanes (amortized: once per 16KB row)
    #pragma unroll
    for (int b = 0; b < 16; ++b) {
        #pragma unroll
        for (int off = 32; off; off >>= 1) p[b] += __shfl_xor(p[b], off, 64);
    }
    const float br = bias[row];
    float vout = p[0];
    #pragma unroll
    for (int b = 1; b < 16; ++b) vout = (lane == b) ? p[b] : vout;
    if (lane < 16) out[(size_t)lane * S + row] = vout + br;
}

// ---------------------------------------------------------------------------
// BISECT PROBE: identical row-per-wave W stream, no x / no FMA consumption.
// If qkv is slow but this is fast -> x-loads are the problem; both slow ->
// the row mapping itself. Dropped once qkv confirms.
// ---------------------------------------------------------------------------
__global__ __launch_bounds__(256, 8) void rowstream_probe(
    const float* __restrict__ Wq, const float* __restrict__ Wk,
    const float* __restrict__ Wv, float* __restrict__ sink)
{
    const int lane = threadIdx.x & 63;
    const int wave = threadIdx.x >> 6;
    const int task = blockIdx.x * 4 + wave;
    const int mat  = task >> 12;
    const int row  = task & 4095;
    const float* W = (mat == 0) ? Wq : (mat == 1) ? Wk : Wv;
    const float* wp = W + (size_t)row * S + lane * 4;

    float sx = 0.f, sy = 0.f, sz = 0.f, sw = 0.f;
    float4 wa = *(const float4*)&wp[0];
    #pragma unroll 1
    for (int ww = 0; ww < 8; ++ww) {
        float4 wb = *(const float4*)&wp[(2 * ww + 1) * 256];
        sx += wa.x; sy += wa.y; sz += wa.z; sw += wa.w;
        if (ww < 7) wa = *(const float4*)&wp[(2 * ww + 2) * 256];
        sx += wb.x; sy += wb.y; sz += wb.z; sw += wb.w;
    }
    float s = sx + sy + sz + sw;
    #pragma unroll
    for (int off = 32; off; off >>= 1) s += __shfl_xor(s, off, 64);
    if (lane == 0) sink[task] = s;
}

// ---------------------------------------------------------------------------
// Inclusive prefix max/min of k per batch row. 16 blocks x 256 threads.
// ---------------------------------------------------------------------------
__global__ __launch_bounds__(256) void scan_kernel(
    const float* __restrict__ k,
    float* __restrict__ rmax, float* __restrict__ rmin)
{
    __shared__ float smax[256], smin[256];
    const int b = blockIdx.x, t = threadIdx.x;
    const float* kb = k + b * S;

    float seg[16];
    float lmax = -INFINITY, lmin = INFINITY;
    #pragma unroll
    for (int e = 0; e < 16; ++e) {
        seg[e] = kb[t * 16 + e];
        lmax = fmaxf(lmax, seg[e]);
        lmin = fminf(lmin, seg[e]);
    }
    smax[t] = lmax; smin[t] = lmin;
    __syncthreads();
    for (int off = 1; off < 256; off <<= 1) {
        float vx = (t >= off) ? smax[t - off] : -INFINITY;
        float vn = (t >= off) ? smin[t - off] :  INFINITY;
        __syncthreads();
        smax[t] = fmaxf(smax[t], vx);
        smin[t] = fminf(smin[t], vn);
        __syncthreads();
    }
    float runmax = (t > 0) ? smax[t - 1] : -INFINITY;
    float runmin = (t > 0) ? smin[t - 1] :  INFINITY;
    #pragma unroll
    for (int e = 0; e < 16; ++e) {
        runmax = fmaxf(runmax, seg[e]);
        runmin = fminf(runmin, seg[e]);
        rmax[b * S + t * 16 + e] = runmax;
        rmin[b * S + t * 16 + e] = runmin;
    }
}

// ---------------------------------------------------------------------------
// d=1 causal attention, single pass (row max known from prefix scan).
// Wave handles R=8 consecutive rows of one batch, sharing k/v loads.
// ---------------------------------------------------------------------------
__global__ __launch_bounds__(256) void attn_kernel(
    const float* __restrict__ q, const float* __restrict__ k,
    const float* __restrict__ v,
    const float* __restrict__ rmax, const float* __restrict__ rmin,
    float* __restrict__ out)
{
    const int tid = threadIdx.x, lane = tid & 63, wave = tid >> 6;
    const int task = blockIdx.x * 4 + wave;     // 0..8191
    const int b    = task & 15;
    const int rbi  = task >> 4;                 // 0..511
    const int i0   = (511 - rbi) * R;           // descending: big rows first
    const float* kb = k + b * S;
    const float* vb = v + b * S;
    const float LOG2E = 1.4426950408889634f;

    float a[R], cc[R], den[R], num[R];
    #pragma unroll
    for (int r = 0; r < R; ++r) {
        float qi = q[b * S + i0 + r];
        float m  = (qi >= 0.f) ? qi * rmax[b * S + i0 + r]
                               : qi * rmin[b * S + i0 + r];
        a[r]  = qi * LOG2E;
        cc[r] = -m * LOG2E;
        den[r] = 0.f; num[r] = 0.f;
    }

    const int nfull = (i0 + 1) >> 8;            // full 256-wide chunks
    #pragma unroll 1
    for (int it = 0; it < nfull; ++it) {
        const int j = it * 256 + lane * 4;
        float4 k4 = *(const float4*)&kb[j];
        float4 v4 = *(const float4*)&vb[j];
        #pragma unroll
        for (int jj = 0; jj < 4; ++jj) {
            float kx = (&k4.x)[jj], vx = (&v4.x)[jj];
            #pragma unroll
            for (int r = 0; r < R; ++r) {
                float e = exp2f(fmaf(a[r], kx, cc[r]));
                den[r] += e;
                num[r] = fmaf(e, vx, num[r]);
            }
        }
    }
    // masked tail
    const int imax = i0 + R - 1;
    for (int j = nfull * 256 + lane; j <= imax; j += 64) {
        float kx = kb[j], vx = vb[j];
        #pragma unroll
        for (int r = 0; r < R; ++r) {
            float e = (j <= i0 + r) ? exp2f(fmaf(a[r], kx, cc[r])) : 0.f;
            den[r] += e;
            num[r] = fmaf(e, vx, num[r]);
        }
    }

    #pragma unroll
    for (int r = 0; r < R; ++r) {
        float d = den[r], n = num[r];
        #pragma unroll
        for (int off = 32; off; off >>= 1) {
            d += __shfl_xor(d, off, 64);
            n += __shfl_xor(n, off, 64);
        }
        if (lane == r) out[b * S + i0 + r] = n / d;
    }
}

extern "C" void kernel_launch(void* const* d_in, const int* in_sizes, int n_in,
                              void* d_out, int out_size, void* d_ws, size_t ws_size,
                              hipStream_t stream) {
    const float* x  = (const float*)d_in[0];
    const float* Wq = (const float*)d_in[1];
    const float* bq = (const float*)d_in[2];
    const float* Wk = (const float*)d_in[3];
    const float* bk = (const float*)d_in[4];
    const float* Wv = (const float*)d_in[5];
    const float* bv = (const float*)d_in[6];
    float* out = (float*)d_out;

    float* ws   = (float*)d_ws;
    float* q    = ws;                // 16*4096
    float* k    = ws + 65536;
    float* v    = ws + 131072;
    float* rmax = ws + 196608;
    float* rmin = ws + 262144;
    float* sink = ws + 327680;       // probe sink (48 KB)

    qkv_kernel<<<3072, 256, 0, stream>>>(x, Wq, bq, Wk, bk, Wv, bv, q, k, v);
    scan_kernel<<<16, 256, 0, stream>>>(k, rmax, rmin);
    attn_kernel<<<2048, 256, 0, stream>>>(q, k, v, rmax, rmin, out);
    rowstream_probe<<<3072, 256, 0, stream>>>(Wq, Wk, Wv, sink);
}

// Round 11
// 106.678 us; speedup vs baseline: 7.6383x; 7.6383x over previous
//
#include <hip/hip_runtime.h>
#include <math.h>

#define S 4096
#define B 16
#define R 8             // attention rows per wave

// ---------------------------------------------------------------------------
// Fused QKV — probe-shaped streaming GEMM. No LDS, no barriers, no prefetch.
// Model (R1-R10): loaded HBM latency ~3000cy -> need >=31KB in flight per CU;
// only free-running issue-then-wait waves achieve it (probe: 6.4 TB/s).
// x-amplification wall: each wave re-reads x; total x L2-traffic =
// 3GB / rows_per_wave -> 4 rows/wave (768 MB, under the 30us W stream).
// Wave = 4 W-rows x 8 batches (p[4][8]=32 regs, no spill, no launch-bound
// pressure); batch-half pairs share a block so the 2nd W read L2-hits.
// Grid: 1536 blocks = 3 mats x 512 groups (8 rows x 16 batches).
// ---------------------------------------------------------------------------
__global__ void qkv_kernel(
    const float* __restrict__ x,
    const float* __restrict__ Wq, const float* __restrict__ bq,
    const float* __restrict__ Wk, const float* __restrict__ bk,
    const float* __restrict__ Wv, const float* __restrict__ bv,
    float* __restrict__ q, float* __restrict__ k, float* __restrict__ v)
{
    const int tid  = threadIdx.x;
    const int lane = tid & 63;
    const int wave = tid >> 6;
    const int bx   = blockIdx.x;        // 0..1535
    const int mat  = bx >> 9;           // 0:q 1:k 2:v
    const int og   = bx & 511;          // 8-row group

    const float* W    = (mat == 0) ? Wq : (mat == 1) ? Wk : Wv;
    const float* bias = (mat == 0) ? bq : (mat == 1) ? bk : bv;
    float*       out  = (mat == 0) ? q  : (mat == 1) ? k  : v;
    const int o0  = og * 8 + (wave >> 1) * 4;   // this wave's 4 W-rows
    const int bb0 = (wave & 1) * 8;             // this wave's 8 batches
    const float* Wp = W + (size_t)o0 * S + lane * 4;
    const float* xp = x + (size_t)bb0 * S + lane * 4;

    float acc[4][8];
    #pragma unroll
    for (int r = 0; r < 4; ++r)
        #pragma unroll
        for (int bi = 0; bi < 8; ++bi) acc[r][bi] = 0.f;

    #pragma unroll 1
    for (int w = 0; w < 16; ++w) {
        const int off = w * 256;
        float4 w0 = *(const float4*)&Wp[(size_t)0 * S + off];
        float4 w1 = *(const float4*)&Wp[(size_t)1 * S + off];
        float4 w2 = *(const float4*)&Wp[(size_t)2 * S + off];
        float4 w3 = *(const float4*)&Wp[(size_t)3 * S + off];
        #pragma unroll
        for (int bi = 0; bi < 8; ++bi) {
            float4 xv = *(const float4*)&xp[(size_t)bi * S + off];
            acc[0][bi] = fmaf(w0.x, xv.x, acc[0][bi]);
            acc[0][bi] = fmaf(w0.y, xv.y, acc[0][bi]);
            acc[0][bi] = fmaf(w0.z, xv.z, acc[0][bi]);
            acc[0][bi] = fmaf(w0.w, xv.w, acc[0][bi]);
            acc[1][bi] = fmaf(w1.x, xv.x, acc[1][bi]);
            acc[1][bi] = fmaf(w1.y, xv.y, acc[1][bi]);
            acc[1][bi] = fmaf(w1.z, xv.z, acc[1][bi]);
            acc[1][bi] = fmaf(w1.w, xv.w, acc[1][bi]);
            acc[2][bi] = fmaf(w2.x, xv.x, acc[2][bi]);
            acc[2][bi] = fmaf(w2.y, xv.y, acc[2][bi]);
            acc[2][bi] = fmaf(w2.z, xv.z, acc[2][bi]);
            acc[2][bi] = fmaf(w2.w, xv.w, acc[2][bi]);
            acc[3][bi] = fmaf(w3.x, xv.x, acc[3][bi]);
            acc[3][bi] = fmaf(w3.y, xv.y, acc[3][bi]);
            acc[3][bi] = fmaf(w3.z, xv.z, acc[3][bi]);
            acc[3][bi] = fmaf(w3.w, xv.w, acc[3][bi]);
        }
    }

    // cross-lane reduction; lane (r*8+bi) writes output (bb0+bi, o0+r)
    // (identical to R3/R4's validated epilogue)
    #pragma unroll
    for (int r = 0; r < 4; ++r) {
        #pragma unroll
        for (int bi = 0; bi < 8; ++bi) {
            float s = acc[r][bi];
            #pragma unroll
            for (int off = 32; off; off >>= 1) s += __shfl_xor(s, off, 64);
            if (lane == r * 8 + bi)
                out[(size_t)(bb0 + bi) * S + o0 + r] = s + bias[o0 + r];
        }
    }
}

// ---------------------------------------------------------------------------
// Inclusive prefix max/min of k per batch row. 16 blocks x 256 threads.
// ---------------------------------------------------------------------------
__global__ __launch_bounds__(256) void scan_kernel(
    const float* __restrict__ k,
    float* __restrict__ rmax, float* __restrict__ rmin)
{
    __shared__ float smax[256], smin[256];
    const int b = blockIdx.x, t = threadIdx.x;
    const float* kb = k + b * S;

    float seg[16];
    float lmax = -INFINITY, lmin = INFINITY;
    #pragma unroll
    for (int e = 0; e < 16; ++e) {
        seg[e] = kb[t * 16 + e];
        lmax = fmaxf(lmax, seg[e]);
        lmin = fminf(lmin, seg[e]);
    }
    smax[t] = lmax; smin[t] = lmin;
    __syncthreads();
    for (int off = 1; off < 256; off <<= 1) {
        float vx = (t >= off) ? smax[t - off] : -INFINITY;
        float vn = (t >= off) ? smin[t - off] :  INFINITY;
        __syncthreads();
        smax[t] = fmaxf(smax[t], vx);
        smin[t] = fminf(smin[t], vn);
        __syncthreads();
    }
    float runmax = (t > 0) ? smax[t - 1] : -INFINITY;
    float runmin = (t > 0) ? smin[t - 1] :  INFINITY;
    #pragma unroll
    for (int e = 0; e < 16; ++e) {
        runmax = fmaxf(runmax, seg[e]);
        runmin = fminf(runmin, seg[e]);
        rmax[b * S + t * 16 + e] = runmax;
        rmin[b * S + t * 16 + e] = runmin;
    }
}

// ---------------------------------------------------------------------------
// d=1 causal attention, single pass (row max known from prefix scan).
// Wave handles R=8 consecutive rows of one batch, sharing k/v loads.
// ---------------------------------------------------------------------------
__global__ __launch_bounds__(256) void attn_kernel(
    const float* __restrict__ q, const float* __restrict__ k,
    const float* __restrict__ v,
    const float* __restrict__ rmax, const float* __restrict__ rmin,
    float* __restrict__ out)
{
    const int tid = threadIdx.x, lane = tid & 63, wave = tid >> 6;
    const int task = blockIdx.x * 4 + wave;     // 0..8191
    const int b    = task & 15;
    const int rbi  = task >> 4;                 // 0..511
    const int i0   = (511 - rbi) * R;           // descending: big rows first
    const float* kb = k + b * S;
    const float* vb = v + b * S;
    const float LOG2E = 1.4426950408889634f;

    float a[R], cc[R], den[R], num[R];
    #pragma unroll
    for (int r = 0; r < R; ++r) {
        float qi = q[b * S + i0 + r];
        float m  = (qi >= 0.f) ? qi * rmax[b * S + i0 + r]
                               : qi * rmin[b * S + i0 + r];
        a[r]  = qi * LOG2E;
        cc[r] = -m * LOG2E;
        den[r] = 0.f; num[r] = 0.f;
    }

    const int nfull = (i0 + 1) >> 8;            // full 256-wide chunks
    #pragma unroll 1
    for (int it = 0; it < nfull; ++it) {
        const int j = it * 256 + lane * 4;
        float4 k4 = *(const float4*)&kb[j];
        float4 v4 = *(const float4*)&vb[j];
        #pragma unroll
        for (int jj = 0; jj < 4; ++jj) {
            float kx = (&k4.x)[jj], vx = (&v4.x)[jj];
            #pragma unroll
            for (int r = 0; r < R; ++r) {
                float e = exp2f(fmaf(a[r], kx, cc[r]));
                den[r] += e;
                num[r] = fmaf(e, vx, num[r]);
            }
        }
    }
    // masked tail
    const int imax = i0 + R - 1;
    for (int j = nfull * 256 + lane; j <= imax; j += 64) {
        float kx = kb[j], vx = vb[j];
        #pragma unroll
        for (int r = 0; r < R; ++r) {
            float e = (j <= i0 + r) ? exp2f(fmaf(a[r], kx, cc[r])) : 0.f;
            den[r] += e;
            num[r] = fmaf(e, vx, num[r]);
        }
    }

    #pragma unroll
    for (int r = 0; r < R; ++r) {
        float d = den[r], n = num[r];
        #pragma unroll
        for (int off = 32; off; off >>= 1) {
            d += __shfl_xor(d, off, 64);
            n += __shfl_xor(n, off, 64);
        }
        if (lane == r) out[b * S + i0 + r] = n / d;
    }
}

extern "C" void kernel_launch(void* const* d_in, const int* in_sizes, int n_in,
                              void* d_out, int out_size, void* d_ws, size_t ws_size,
                              hipStream_t stream) {
    const float* x  = (const float*)d_in[0];
    const float* Wq = (const float*)d_in[1];
    const float* bq = (const float*)d_in[2];
    const float* Wk = (const float*)d_in[3];
    const float* bk = (const float*)d_in[4];
    const float* Wv = (const float*)d_in[5];
    const float* bv = (const float*)d_in[6];
    float* out = (float*)d_out;

    float* ws   = (float*)d_ws;
    float* q    = ws;                // 16*4096
    float* k    = ws + 65536;
    float* v    = ws + 131072;
    float* rmax = ws + 196608;
    float* rmin = ws + 262144;       // total 1.25 MB scratch

    qkv_kernel<<<1536, 256, 0, stream>>>(x, Wq, bq, Wk, bk, Wv, bv, q, k, v);
    scan_kernel<<<16, 256, 0, stream>>>(k, rmax, rmin);
    attn_kernel<<<2048, 256, 0, stream>>>(q, k, v, rmax, rmin, out);
}